// Round 10
// baseline (191.199 us; speedup 1.0000x reference)
//
#include <hip/hip_runtime.h>

typedef short  s8v   __attribute__((ext_vector_type(8)));
typedef float  f32x4 __attribute__((ext_vector_type(4)));

#define SEQ 2048
#define WID 768

__device__ __forceinline__ unsigned fbits(float f) {
    union { float f; unsigned u; } v; v.f = f; return v.u;
}
__device__ __forceinline__ float bitsf(unsigned u) {
    union { unsigned u; float f; } v; v.u = u; return v.f;
}
__device__ __forceinline__ unsigned short f2b(float f) {
    unsigned u = fbits(f);
    return (unsigned short)((u + 0x7FFFu + ((u >> 16) & 1u)) >> 16);   // RNE
}
__device__ __forceinline__ unsigned packRNE(float a, float b) {
    unsigned ta = fbits(a) + 0x7FFFu + ((fbits(a) >> 16) & 1u);
    unsigned tb = fbits(b) + 0x7FFFu + ((fbits(b) >> 16) & 1u);
    return __builtin_amdgcn_perm(tb, ta, 0x07060302u);
}
__device__ __forceinline__ unsigned packTRUNC(float a, float b) {
    return __builtin_amdgcn_perm(fbits(b), fbits(a), 0x07060302u);
}
__device__ __forceinline__ f32x4 zero4() { f32x4 z = {0.f, 0.f, 0.f, 0.f}; return z; }

// async global->LDS DMA, 16B/lane.  Global address is PER-LANE (gather ok);
// LDS dest = wave-uniform base + lane*16.
__device__ __forceinline__ void async16(const unsigned short* g, void* l) {
    __builtin_amdgcn_global_load_lds(
        (const __attribute__((address_space(1))) unsigned int*)g,
        (__attribute__((address_space(3))) unsigned int*)l, 16, 0, 0);
}
__device__ __forceinline__ void async16f(const float* g, void* l) {
    __builtin_amdgcn_global_load_lds(
        (const __attribute__((address_space(1))) unsigned int*)g,
        (__attribute__((address_space(3))) unsigned int*)l, 16, 0, 0);
}

// ---------------------------------------------------------------------------
// convert_mask: mask -> PM bit-packing (verbatim verified logic).
// ---------------------------------------------------------------------------
__global__ __launch_bounds__(256) void convert_mask_kernel(
    const int* __restrict__ mask, unsigned* __restrict__ PM)
{
    const int tid = threadIdx.x;
    const int gid  = blockIdx.x * 4 + (tid >> 6);
    const int lane = tid & 63, quad = lane >> 4, c = lane & 15;
    const int qb = gid >> 5, kb = gid & 31;
    unsigned w = 0;
    #pragma unroll
    for (int mt = 0; mt < 2; ++mt)
        #pragma unroll
        for (int i = 0; i < 4; ++i) {
            const int q = qb * 32 + mt * 16 + quad * 4 + i;
            const int4 mm = *(const int4*)&mask[(size_t)q * SEQ + kb * 64 + 4 * c];
            if (mm.x) w |= 1u << (mt * 16 + i * 4 + 0);
            if (mm.y) w |= 1u << (mt * 16 + i * 4 + 1);
            if (mm.z) w |= 1u << (mt * 16 + i * 4 + 2);
            if (mm.w) w |= 1u << (mt * 16 + i * 4 + 3);
        }
    PM[(size_t)gid * 64 + lane] = w;
}

// ---------------------------------------------------------------------------
// convert_w: W -> WF bf16 B-frag-tiled (verbatim verified logic).
// ---------------------------------------------------------------------------
__global__ __launch_bounds__(256) void convert_w_kernel(
    const float* __restrict__ Wq, const float* __restrict__ Wk, const float* __restrict__ Wv,
    unsigned short* __restrict__ WF)
{
    const int s2 = blockIdx.x * 256 + threadIdx.x;   // 0 .. 18431
    const int chunk = s2 >> 6, l = s2 & 63;
    const int ntg = chunk / 24, r = chunk - ntg * 24;
    const int kc = r >> 1, h = r & 1;
    const int mat = ntg >> 2;
    const int col = (ntg & 3) * 16 + (l & 15);
    const int k0 = kc * 64 + h * 32 + (l >> 4) * 8;
    const float* Wm = (mat == 0) ? Wq : (mat == 1) ? Wk : Wv;
    float p[8];
    #pragma unroll
    for (int j = 0; j < 8; ++j) p[j] = Wm[(size_t)(k0 + j) * 64 + col];
    uint4 w;
    w.x = packRNE(p[0], p[1]); w.y = packRNE(p[2], p[3]);
    w.z = packRNE(p[4], p[5]); w.w = packRNE(p[6], p[7]);
    *(uint4*)&WF[(size_t)s2 * 8] = w;
}

// ---------------------------------------------------------------------------
// proj: DMA-pipelined bf16 GEMM.  256 blocks x 512 thr (8 waves; wave =
// 32r x 48c via rg=wv>>2, cg=wv&3).  BK=32, 24 iters.  BOTH operands staged
// via global_load_lds (fire-and-forget, unsinkable):
//   x: per-lane GATHER addresses, landing in A-frag order (fp32; packRNE at
//      read time, 8/iter/wave); WF: contiguous 1KB chunks.
// Double-buffered (20KB/buf), ONE barrier per iteration: barrier publishes
// buf b (drains DMAs issued one full compute phase earlier); re-write of b
// happens after the NEXT barrier, so no tail barrier is needed.
// Epilogue: R8's verified frag-tiled QF/KF/VF writeback (verbatim).
// ---------------------------------------------------------------------------
__global__ __launch_bounds__(512, 2) void qkv_proj_kernel(
    const float* __restrict__ x, const unsigned short* __restrict__ WF,
    const float* __restrict__ bq, const float* __restrict__ bk, const float* __restrict__ bv,
    unsigned short* __restrict__ QF, unsigned short* __restrict__ KF,
    unsigned short* __restrict__ VF)
{
    __shared__ __align__(16) unsigned char SM[40960];   // 2 x (8KB x + 12KB W)
    unsigned short (*St)[200] = (unsigned short(*)[200])SM;   // epilogue overlay

    const int tid = threadIdx.x;
    const int wv = tid >> 6, lane = tid & 63, quad = lane >> 4, c = lane & 15;
    const int rg = wv >> 2, cg = wv & 3;
    const int rowb = blockIdx.x * 64;

    float bias[3];
    #pragma unroll
    for (int nt = 0; nt < 3; ++nt) {
        int col = cg * 48 + nt * 16 + c;
        const float* B = (col < 64) ? bq : (col < 128) ? bk : bv;
        bias[nt] = B[col & 63];
    }

    // DMA all 20 chunks of iteration kc into buffer b (waves split the work)
    auto issue = [&](int kc, int b) {
        unsigned char* base = SM + b * 20480;
        #pragma unroll
        for (int t0 = 0; t0 < 3; ++t0) {
            const int t = wv + 8 * t0;
            if (t < 8) {          // x chunk: frag g = t>>1, half j = t&1 (per-lane gather)
                const int g = t >> 1, j = t & 1;
                const float* src = x + (size_t)(rowb + g * 16 + c) * WID
                                     + kc * 32 + quad * 8 + j * 4;
                async16f(src, base + (g * 2 + j) * 1024);
            } else if (t < 20) {  // W chunk i = t-8 (contiguous 1KB)
                const int i = t - 8;
                const unsigned short* src =
                    WF + (((size_t)i * 12 + (kc >> 1)) * 2 + (kc & 1)) * 512 + lane * 8;
                async16(src, base + 8192 + i * 1024);
            }
        }
    };

    f32x4 acc[2][3];
    #pragma unroll
    for (int mt = 0; mt < 2; ++mt)
        #pragma unroll
        for (int nt = 0; nt < 3; ++nt) acc[mt][nt] = zero4();

    issue(0, 0);
    for (int kc = 0; kc < 24; ++kc) {
        const int b = kc & 1;
        __syncthreads();                      // publish buf b
        if (kc < 23) issue(kc + 1, b ^ 1);    // overlaps the compute below

        const unsigned char* base = SM + b * 20480;
        s8v af[2];
        #pragma unroll
        for (int mt = 0; mt < 2; ++mt) {
            const int g = rg * 2 + mt;
            float4 f0 = *(const float4*)(base + (g * 2 + 0) * 1024 + lane * 16);
            float4 f1 = *(const float4*)(base + (g * 2 + 1) * 1024 + lane * 16);
            union { uint4 u; s8v v; } a;
            a.u.x = packRNE(f0.x, f0.y);
            a.u.y = packRNE(f0.z, f0.w);
            a.u.z = packRNE(f1.x, f1.y);
            a.u.w = packRNE(f1.z, f1.w);
            af[mt] = a.v;
        }
        s8v bf[3];
        #pragma unroll
        for (int nt = 0; nt < 3; ++nt)
            bf[nt] = *(const s8v*)(base + 8192 + (cg * 3 + nt) * 1024 + lane * 16);
        #pragma unroll
        for (int mt = 0; mt < 2; ++mt)
            #pragma unroll
            for (int nt = 0; nt < 3; ++nt)
                acc[mt][nt] = __builtin_amdgcn_mfma_f32_16x16x32_bf16(
                    af[mt], bf[nt], acc[mt][nt], 0, 0, 0);
    }

    // ---- epilogue: bias + stage 64x192 bf16 tile (overlay; barrier first)
    __syncthreads();
    #pragma unroll
    for (int mt = 0; mt < 2; ++mt)
        #pragma unroll
        for (int nt = 0; nt < 3; ++nt)
            #pragma unroll
            for (int i = 0; i < 4; ++i)
                St[rg * 32 + mt * 16 + quad * 4 + i][cg * 48 + nt * 16 + c]
                    = f2b(acc[mt][nt][i] + bias[nt]);
    __syncthreads();

    const int blk = blockIdx.x;
    const int g0 = blk * 4;
    {   // QF
        const int g = tid >> 7, ks = (tid >> 6) & 1, l = tid & 63;
        uint4 v = *(uint4*)&St[g * 16 + (l & 15)][ks * 32 + (l >> 4) * 8];
        *(uint4*)&QF[(((size_t)(g0 + g)) * 2 + ks) * 512 + (size_t)l * 8] = v;
    }
    {   // KF
        const int ksnt = tid >> 6, l = tid & 63;
        const int ks = ksnt >> 2, nt = ksnt & 3;
        uint4 v = *(uint4*)&St[4 * (l & 15) + nt][64 + ks * 32 + (l >> 4) * 8];
        *(uint4*)&KF[(((size_t)blk * 8 + ksnt) * 64 + l) * 8] = v;
    }
    {   // VF
        const int ksnt = tid >> 6, l = tid & 63;
        const int ks = ksnt >> 2, nt = ksnt & 3;
        const int d = 128 + nt * 16 + (l & 15);
        const int r0 = ks * 32 + (l >> 4) * 8;
        unsigned short p[8];
        #pragma unroll
        for (int s = 0; s < 8; ++s) p[s] = St[r0 + s][d];
        uint4 w;
        w.x = (unsigned)p[0] | ((unsigned)p[1] << 16);
        w.y = (unsigned)p[2] | ((unsigned)p[3] << 16);
        w.z = (unsigned)p[4] | ((unsigned)p[5] << 16);
        w.w = (unsigned)p[6] | ((unsigned)p[7] << 16);
        *(uint4*)&VF[(((size_t)blk * 8 + ksnt) * 64 + l) * 8] = w;
    }
}

// ---------------------------------------------------------------------------
// attn: barrier-free flash attention (R9 verbatim math) + EXPLICIT next-iter
// K/V/PM register prefetch, __launch_bounds__(256,2) -> 256-VGPR cap so the
// ~180 live regs fit without spill.  Grid 1024 (bb = blk&7 XCD swizzle).
// Tq=16/wave, 4 slices of 512 keys, Ps wave-private, one merge barrier.
// ---------------------------------------------------------------------------
__global__ __launch_bounds__(256, 2) void attn_kernel(
    const unsigned short* __restrict__ QF, const unsigned short* __restrict__ KF,
    const unsigned short* __restrict__ VF, const unsigned* __restrict__ PM,
    float* __restrict__ out)
{
    __shared__ unsigned short Ps[4][16][72];
    __shared__ float Obuf[16][68];
    __shared__ float Lbuf[16];

    const int tid = threadIdx.x;
    const int wv = tid >> 6, lane = tid & 63, quad = lane >> 4, c = lane & 15;
    const int blk = blockIdx.x;
    const int bb = blk & 7, g = blk >> 3;
    const int qb32 = g >> 1, mtq = g & 1;

    #pragma unroll
    for (int j = 0; j < 5; ++j) {
        int idx = tid + 256 * j;
        if (idx < 16 * 68) ((float*)Obuf)[idx] = 0.f;
    }
    if (tid < 16) Lbuf[tid] = 0.f;

    s8v qf[2];
    {
        const size_t qgrp = (size_t)bb * 128 + g;
        #pragma unroll
        for (int ks = 0; ks < 2; ++ks)
            qf[ks] = *(const s8v*)&QF[(qgrp * 2 + ks) * 512 + (size_t)lane * 8];
    }

    f32x4 O[4];
    float lro[4];
    #pragma unroll
    for (int nt = 0; nt < 4; ++nt) O[nt] = zero4();
    #pragma unroll
    for (int i = 0; i < 4; ++i) lro[i] = 0.f;

    // prefetch kt=0
    s8v kf[8], vf[8];
    unsigned pm;
    {
        const size_t kbg = (size_t)bb * 32 + wv * 8;
        #pragma unroll
        for (int ch = 0; ch < 8; ++ch) {
            kf[ch] = *(const s8v*)&KF[(kbg * 8 + ch) * 512 + (size_t)lane * 8];
            vf[ch] = *(const s8v*)&VF[(kbg * 8 + ch) * 512 + (size_t)lane * 8];
        }
        pm = PM[(size_t)(qb32 * 32 + wv * 8) * 64 + lane];
    }

    #pragma unroll
    for (int kt = 0; kt < 8; ++kt) {
        // issue next-iter prefetch FIRST (hoisted loads; budget allows holding)
        s8v kfn[8], vfn[8];
        unsigned pmn = 0;
        if (kt < 7) {
            const size_t kbgn = (size_t)bb * 32 + wv * 8 + kt + 1;
            #pragma unroll
            for (int ch = 0; ch < 8; ++ch) {
                kfn[ch] = *(const s8v*)&KF[(kbgn * 8 + ch) * 512 + (size_t)lane * 8];
                vfn[ch] = *(const s8v*)&VF[(kbgn * 8 + ch) * 512 + (size_t)lane * 8];
            }
            pmn = PM[(size_t)(qb32 * 32 + wv * 8 + kt + 1) * 64 + lane];
        }

        // ---- S = Q K^T
        f32x4 S[4];
        #pragma unroll
        for (int nt = 0; nt < 4; ++nt) S[nt] = zero4();
        #pragma unroll
        for (int ks = 0; ks < 2; ++ks)
            #pragma unroll
            for (int nt = 0; nt < 4; ++nt)
                S[nt] = __builtin_amdgcn_mfma_f32_16x16x32_bf16(qf[ks], kf[ks * 4 + nt], S[nt], 0, 0, 0);

        // ---- fixed-shift softmax: p = 2^(s*0.125/ln2 - 15/ln2), masked -> 0
        const unsigned pmh = pm >> (mtq * 16);
        #pragma unroll
        for (int i = 0; i < 4; ++i) {
            float p4[4];
            #pragma unroll
            for (int nt = 0; nt < 4; ++nt) {
                float e = exp2f(fmaf(S[nt][i], 0.18033688011112042f, -21.640425613334451f));
                p4[nt] = ((pmh >> (i * 4 + nt)) & 1u) ? e : 0.f;
            }
            unsigned u0 = packTRUNC(p4[0], p4[1]);
            unsigned u1 = packTRUNC(p4[2], p4[3]);
            lro[i] += bitsf(u0 << 16) + bitsf(u0 & 0xFFFF0000u)
                    + bitsf(u1 << 16) + bitsf(u1 & 0xFFFF0000u);
            *(uint2*)&Ps[wv][quad * 4 + i][4 * c] = make_uint2(u0, u1);
        }

        // ---- O += P V (Ps wave-private: lgkm ordering, no barrier)
        #pragma unroll
        for (int ks = 0; ks < 2; ++ks) {
            s8v a = *(const s8v*)&Ps[wv][c][ks * 32 + quad * 8];
            #pragma unroll
            for (int nt = 0; nt < 4; ++nt)
                O[nt] = __builtin_amdgcn_mfma_f32_16x16x32_bf16(a, vf[ks * 4 + nt], O[nt], 0, 0, 0);
        }

        // rotate prefetch
        #pragma unroll
        for (int ch = 0; ch < 8; ++ch) { kf[ch] = kfn[ch]; vf[ch] = vfn[ch]; }
        pm = pmn;
    }

    // ---- merge 4 slices
    __syncthreads();
    #pragma unroll
    for (int i = 0; i < 4; ++i) {
        float l = lro[i];
        l += __shfl_xor(l, 1);
        l += __shfl_xor(l, 2);
        l += __shfl_xor(l, 4);
        l += __shfl_xor(l, 8);
        if (c == 0) atomicAdd(&Lbuf[quad * 4 + i], l);
        #pragma unroll
        for (int nt = 0; nt < 4; ++nt)
            atomicAdd(&Obuf[quad * 4 + i][nt * 16 + c], O[nt][i]);
    }
    __syncthreads();
    {
        const int r = tid >> 4, d4 = (tid & 15) * 4;
        const float invL = 1.0f / Lbuf[r];
        float4 v = *(float4*)&Obuf[r][d4];
        float4 o = make_float4(v.x * invL, v.y * invL, v.z * invL, v.w * invL);
        *(float4*)&out[((size_t)bb * SEQ + g * 16 + r) * 64 + d4] = o;
    }
}

extern "C" void kernel_launch(void* const* d_in, const int* in_sizes, int n_in,
                              void* d_out, int out_size, void* d_ws, size_t ws_size,
                              hipStream_t stream)
{
    const float* x    = (const float*)d_in[0];
    const float* Wq   = (const float*)d_in[1];
    const float* bq   = (const float*)d_in[2];
    const float* Wk   = (const float*)d_in[3];
    const float* bk   = (const float*)d_in[4];
    const float* Wv   = (const float*)d_in[5];
    const float* bv   = (const float*)d_in[6];
    const int*   mask = (const int*)d_in[7];
    float* out = (float*)d_out;

    unsigned short* QF = (unsigned short*)d_ws;
    unsigned short* KF = QF + (size_t)16384 * 64;
    unsigned short* VF = KF + (size_t)16384 * 64;
    unsigned short* WF = VF + (size_t)16384 * 64;
    unsigned*       PM = (unsigned*)(WF + (size_t)192 * WID);

    convert_mask_kernel<<<512, 256, 0, stream>>>(mask, PM);
    convert_w_kernel<<<72, 256, 0, stream>>>(Wq, Wk, Wv, WF);
    qkv_proj_kernel<<<256, 512, 0, stream>>>(x, WF, bq, bk, bv, QF, KF, VF);
    attn_kernel<<<1024, 256, 0, stream>>>(QF, KF, VF, PM, out);
}

// Round 11
// 190.748 us; speedup vs baseline: 1.0024x; 1.0024x over previous
//
#include <hip/hip_runtime.h>

typedef short  s8v   __attribute__((ext_vector_type(8)));
typedef float  f32x4 __attribute__((ext_vector_type(4)));

#define SEQ 2048
#define WID 768

__device__ __forceinline__ unsigned fbits(float f) {
    union { float f; unsigned u; } v; v.f = f; return v.u;
}
__device__ __forceinline__ float bitsf(unsigned u) {
    union { unsigned u; float f; } v; v.u = u; return v.f;
}
__device__ __forceinline__ unsigned short f2b(float f) {
    unsigned u = fbits(f);
    return (unsigned short)((u + 0x7FFFu + ((u >> 16) & 1u)) >> 16);   // RNE
}
__device__ __forceinline__ unsigned packRNE(float a, float b) {
    unsigned ta = fbits(a) + 0x7FFFu + ((fbits(a) >> 16) & 1u);
    unsigned tb = fbits(b) + 0x7FFFu + ((fbits(b) >> 16) & 1u);
    return __builtin_amdgcn_perm(tb, ta, 0x07060302u);
}
__device__ __forceinline__ unsigned packTRUNC(float a, float b) {
    return __builtin_amdgcn_perm(fbits(b), fbits(a), 0x07060302u);
}
__device__ __forceinline__ f32x4 zero4() { f32x4 z = {0.f, 0.f, 0.f, 0.f}; return z; }

// async global->LDS DMA, 16B/lane; per-lane global address, wave-uniform LDS base
__device__ __forceinline__ void async16(const unsigned short* g, void* l) {
    __builtin_amdgcn_global_load_lds(
        (const __attribute__((address_space(1))) unsigned int*)g,
        (__attribute__((address_space(3))) unsigned int*)l, 16, 0, 0);
}
__device__ __forceinline__ void async16f(const float* g, void* l) {
    __builtin_amdgcn_global_load_lds(
        (const __attribute__((address_space(1))) unsigned int*)g,
        (__attribute__((address_space(3))) unsigned int*)l, 16, 0, 0);
}

// ---------------------------------------------------------------------------
// convert_w: W -> WF bf16 B-frag-tiled (verbatim verified logic).
// ---------------------------------------------------------------------------
__global__ __launch_bounds__(256) void convert_w_kernel(
    const float* __restrict__ Wq, const float* __restrict__ Wk, const float* __restrict__ Wv,
    unsigned short* __restrict__ WF)
{
    const int s2 = blockIdx.x * 256 + threadIdx.x;   // 0 .. 18431
    const int chunk = s2 >> 6, l = s2 & 63;
    const int ntg = chunk / 24, r = chunk - ntg * 24;
    const int kc = r >> 1, h = r & 1;
    const int mat = ntg >> 2;
    const int col = (ntg & 3) * 16 + (l & 15);
    const int k0 = kc * 64 + h * 32 + (l >> 4) * 8;
    const float* Wm = (mat == 0) ? Wq : (mat == 1) ? Wk : Wv;
    float p[8];
    #pragma unroll
    for (int j = 0; j < 8; ++j) p[j] = Wm[(size_t)(k0 + j) * 64 + col];
    uint4 w;
    w.x = packRNE(p[0], p[1]); w.y = packRNE(p[2], p[3]);
    w.z = packRNE(p[4], p[5]); w.w = packRNE(p[6], p[7]);
    *(uint4*)&WF[(size_t)s2 * 8] = w;
}

// ---------------------------------------------------------------------------
// proj: DMA-pipelined bf16 GEMM.  512 blocks x 256 thr (2 blocks/CU @32KB
// LDS).  Block tile = 32 rows x 192 cols; wave = 32r x 48c (cg = wv).
// BK=32, 24 iters.  Both operands via global_load_lds (unsinkable):
// x per-lane gather into A-frag order; WF contiguous 1KB chunks.  Double-
// buffered (16KB/buf), ONE barrier/iter.  Epilogue: frag-tiled QF/KF/VF
// writeback re-derived for 32-row blocks against the frozen layouts.
// ---------------------------------------------------------------------------
__global__ __launch_bounds__(256, 4) void qkv_proj_kernel(
    const float* __restrict__ x, const unsigned short* __restrict__ WF,
    const float* __restrict__ bq, const float* __restrict__ bk, const float* __restrict__ bv,
    unsigned short* __restrict__ QF, unsigned short* __restrict__ KF,
    unsigned short* __restrict__ VF)
{
    __shared__ __align__(16) unsigned char SM[32768];   // 2 x (4KB x + 12KB W)
    unsigned short (*St)[200] = (unsigned short(*)[200])SM;   // epilogue overlay

    const int tid = threadIdx.x;
    const int wv = tid >> 6, lane = tid & 63, quad = lane >> 4, c = lane & 15;
    const int cg = wv;
    const int rowb = blockIdx.x * 32;

    float bias[3];
    #pragma unroll
    for (int nt = 0; nt < 3; ++nt) {
        int col = cg * 48 + nt * 16 + c;
        const float* B = (col < 64) ? bq : (col < 128) ? bk : bv;
        bias[nt] = B[col & 63];
    }

    // 16 chunks/iter (4 x + 12 W), 4 per wave
    auto issue = [&](int kc, int b) {
        unsigned char* base = SM + b * 16384;
        #pragma unroll
        for (int r = 0; r < 4; ++r) {
            const int t = wv * 4 + r;
            if (t < 4) {          // x chunk: m-tile mt = t>>1, j-half jh = t&1
                const int mt = t >> 1, jh = t & 1;
                const float* src = x + (size_t)(rowb + mt * 16 + c) * WID
                                     + kc * 32 + quad * 8 + jh * 4;
                async16f(src, base + (mt * 2 + jh) * 1024);
            } else {              // W chunk i = t-4
                const int i = t - 4;
                const unsigned short* src =
                    WF + (((size_t)i * 12 + (kc >> 1)) * 2 + (kc & 1)) * 512 + lane * 8;
                async16(src, base + 4096 + i * 1024);
            }
        }
    };

    f32x4 acc[2][3];
    #pragma unroll
    for (int mt = 0; mt < 2; ++mt)
        #pragma unroll
        for (int nt = 0; nt < 3; ++nt) acc[mt][nt] = zero4();

    issue(0, 0);
    for (int kc = 0; kc < 24; ++kc) {
        const int b = kc & 1;
        __syncthreads();                      // publish buf b
        if (kc < 23) issue(kc + 1, b ^ 1);    // overlaps compute below

        const unsigned char* base = SM + b * 16384;
        s8v af[2];
        #pragma unroll
        for (int mt = 0; mt < 2; ++mt) {
            float4 f0 = *(const float4*)(base + (mt * 2 + 0) * 1024 + lane * 16);
            float4 f1 = *(const float4*)(base + (mt * 2 + 1) * 1024 + lane * 16);
            union { uint4 u; s8v v; } a;
            a.u.x = packRNE(f0.x, f0.y);
            a.u.y = packRNE(f0.z, f0.w);
            a.u.z = packRNE(f1.x, f1.y);
            a.u.w = packRNE(f1.z, f1.w);
            af[mt] = a.v;
        }
        s8v bf[3];
        #pragma unroll
        for (int nt = 0; nt < 3; ++nt)
            bf[nt] = *(const s8v*)(base + 4096 + (cg * 3 + nt) * 1024 + lane * 16);
        #pragma unroll
        for (int mt = 0; mt < 2; ++mt)
            #pragma unroll
            for (int nt = 0; nt < 3; ++nt)
                acc[mt][nt] = __builtin_amdgcn_mfma_f32_16x16x32_bf16(
                    af[mt], bf[nt], acc[mt][nt], 0, 0, 0);
    }

    // ---- epilogue: bias + stage 32x192 bf16 tile (overlay after barrier)
    __syncthreads();
    #pragma unroll
    for (int mt = 0; mt < 2; ++mt)
        #pragma unroll
        for (int nt = 0; nt < 3; ++nt)
            #pragma unroll
            for (int i = 0; i < 4; ++i)
                St[mt * 16 + quad * 4 + i][cg * 48 + nt * 16 + c]
                    = f2b(acc[mt][nt][i] + bias[nt]);
    __syncthreads();

    const int kb  = rowb >> 6;
    const int q0k = (rowb & 63) >> 2;    // 0 or 8
    const int ks0 = (rowb & 63) >> 5;    // 0 or 1

    {   // QF: g = tid>>7 (16-row grp), ks = (tid>>6)&1, l = tid&63
        const int g = tid >> 7, ks = (tid >> 6) & 1, l = tid & 63;
        uint4 v = *(uint4*)&St[g * 16 + (l & 15)][ks * 32 + (l >> 4) * 8];
        *(uint4*)&QF[(((size_t)(rowb >> 4) + g) * 2 + ks) * 512 + (size_t)l * 8] = v;
    }
    {   // KF: ksnt = tid>>5, e = tid&31 -> qd = e>>3, cc = e&7
        const int ksnt = tid >> 5, e = tid & 31;
        const int ks = ksnt >> 2, nt = ksnt & 3;
        const int qd = e >> 3, cc = e & 7;
        uint4 v = *(uint4*)&St[4 * cc + nt][64 + ks * 32 + qd * 8];
        *(uint4*)&KF[(((size_t)kb * 8 + ksnt) * 64 + qd * 16 + q0k + cc) * 8] = v;
    }
    {   // VF: nt = tid>>6, qd = (tid>>4)&3, cc = tid&15
        const int nt = tid >> 6, qd = (tid >> 4) & 3, cc = tid & 15;
        unsigned short p[8];
        #pragma unroll
        for (int s = 0; s < 8; ++s) p[s] = St[qd * 8 + s][128 + nt * 16 + cc];
        uint4 w;
        w.x = (unsigned)p[0] | ((unsigned)p[1] << 16);
        w.y = (unsigned)p[2] | ((unsigned)p[3] << 16);
        w.z = (unsigned)p[4] | ((unsigned)p[5] << 16);
        w.w = (unsigned)p[6] | ((unsigned)p[7] << 16);
        *(uint4*)&VF[(((size_t)kb * 8 + ks0 * 4 + nt) * 64 + qd * 16 + cc) * 8] = w;
    }
}

// ---------------------------------------------------------------------------
// attn: flash attention, MFMA bf16, fixed-shift softmax (verbatim verified
// math).  512 thr = 8 waves = 4 key-slices x 2 q-halves; block = 32 q x
// 2048 keys; grid 512 (bb = blk&7 XCD swizzle) -> 2 blocks/CU, 16 waves/CU.
// K tile per slice DMA'd to LDS (8KB, shared by 2 waves); V direct b128
// loads under the softmax shadow; mask read DIRECTLY (int4 gathers,
// L3-resident, shared across batches) - no PM pass.  2 barriers/iter;
// cross-block overlap covers the DMA drain.
// ---------------------------------------------------------------------------
__global__ __launch_bounds__(512, 4) void attn_kernel(
    const unsigned short* __restrict__ QF, const unsigned short* __restrict__ KF,
    const unsigned short* __restrict__ VF, const int* __restrict__ mask,
    float* __restrict__ out)
{
    __shared__ unsigned short Ks[4][4096];              // 8KB per slice
    __shared__ __align__(16) unsigned char PsOb[17408]; // Ps[8][16][68] ∪ Obuf[32][68]
    __shared__ float Lbuf[32];
    unsigned short (*Ps)[16][68] = (unsigned short(*)[16][68])PsOb;
    float (*Obuf)[68]            = (float(*)[68])PsOb;

    const int tid = threadIdx.x;
    const int wv = tid >> 6, lane = tid & 63, quad = lane >> 4, c = lane & 15;
    const int sl = wv & 3, qh = wv >> 2;
    const int blk = blockIdx.x;
    const int bb = blk & 7, qt = blk >> 3;              // batch, 32-q tile
    const int qrow_blk = qt * 32;

    // Q frags (coalesced 1KB loads)
    s8v qf[2];
    {
        const size_t qgrp = (size_t)bb * 128 + qt * 2 + qh;
        #pragma unroll
        for (int ks = 0; ks < 2; ++ks)
            qf[ks] = *(const s8v*)&QF[(qgrp * 2 + ks) * 512 + (size_t)lane * 8];
    }

    f32x4 O[4];
    float lro[4];
    #pragma unroll
    for (int nt = 0; nt < 4; ++nt) O[nt] = zero4();
    #pragma unroll
    for (int i = 0; i < 4; ++i) lro[i] = 0.f;

    // K DMA for this slice's kt tile: 8 chunks / 2 waves -> 4 each
    auto k_dma = [&](int kt) {
        const size_t kbg = (size_t)bb * 32 + sl * 8 + kt;
        #pragma unroll
        for (int r = 0; r < 4; ++r) {
            const int ch = qh * 4 + r;
            async16(KF + (kbg * 8 + ch) * 512 + lane * 8, &Ks[sl][ch * 512]);
        }
    };

    k_dma(0);
    for (int kt = 0; kt < 8; ++kt) {
        const int kb64 = sl * 8 + kt;
        const size_t kbg = (size_t)bb * 32 + kb64;

        // mask gathers for this tile (independent; L3-resident)
        int4 mrow[4];
        #pragma unroll
        for (int i = 0; i < 4; ++i) {
            const int q = qrow_blk + qh * 16 + quad * 4 + i;
            mrow[i] = *(const int4*)&mask[(size_t)q * SEQ + kb64 * 64 + 4 * c];
        }

        __syncthreads();   // publish Ks (drain DMA)

        // ---- S = Q K^T
        f32x4 S[4];
        #pragma unroll
        for (int nt = 0; nt < 4; ++nt) S[nt] = zero4();
        #pragma unroll
        for (int ks = 0; ks < 2; ++ks) {
            s8v kfr[4];
            #pragma unroll
            for (int nt = 0; nt < 4; ++nt)
                kfr[nt] = *(const s8v*)&Ks[sl][((ks * 4 + nt) * 64 + lane) * 8];
            #pragma unroll
            for (int nt = 0; nt < 4; ++nt)
                S[nt] = __builtin_amdgcn_mfma_f32_16x16x32_bf16(qf[ks], kfr[nt], S[nt], 0, 0, 0);
        }

        // ---- V frags (direct; latency under softmax shadow)
        s8v vf[8];
        #pragma unroll
        for (int ch = 0; ch < 8; ++ch)
            vf[ch] = *(const s8v*)&VF[(kbg * 8 + ch) * 512 + (size_t)lane * 8];

        // ---- fixed-shift softmax: p = 2^(s*0.125/ln2 - 15/ln2), masked -> 0
        #pragma unroll
        for (int i = 0; i < 4; ++i) {
            float p4[4];
            #pragma unroll
            for (int nt = 0; nt < 4; ++nt) {
                float e = exp2f(fmaf(S[nt][i], 0.18033688011112042f, -21.640425613334451f));
                const int mb = (nt == 0) ? mrow[i].x : (nt == 1) ? mrow[i].y
                             : (nt == 2) ? mrow[i].z : mrow[i].w;
                p4[nt] = mb ? e : 0.f;
            }
            unsigned u0 = packTRUNC(p4[0], p4[1]);
            unsigned u1 = packTRUNC(p4[2], p4[3]);
            lro[i] += bitsf(u0 << 16) + bitsf(u0 & 0xFFFF0000u)
                    + bitsf(u1 << 16) + bitsf(u1 & 0xFFFF0000u);
            *(uint2*)&Ps[wv][quad * 4 + i][4 * c] = make_uint2(u0, u1);
        }

        // ---- O += P V  (Ps wave-private: lgkm ordering)
        #pragma unroll
        for (int ks = 0; ks < 2; ++ks) {
            s8v a = *(const s8v*)&Ps[wv][c][ks * 32 + quad * 8];
            #pragma unroll
            for (int nt = 0; nt < 4; ++nt)
                O[nt] = __builtin_amdgcn_mfma_f32_16x16x32_bf16(a, vf[ks * 4 + nt], O[nt], 0, 0, 0);
        }

        __syncthreads();   // Ks reads done
        if (kt < 7) k_dma(kt + 1);
    }

    // ---- merge 4 slices per q-half (Obuf overlays Ps after barrier)
    __syncthreads();
    #pragma unroll
    for (int j = 0; j < 5; ++j) {
        int idx = tid + 512 * j;
        if (idx < 32 * 68) ((float*)Obuf)[idx] = 0.f;
    }
    if (tid < 32) Lbuf[tid] = 0.f;
    __syncthreads();
    #pragma unroll
    for (int i = 0; i < 4; ++i) {
        float l = lro[i];
        l += __shfl_xor(l, 1);
        l += __shfl_xor(l, 2);
        l += __shfl_xor(l, 4);
        l += __shfl_xor(l, 8);
        if (c == 0) atomicAdd(&Lbuf[qh * 16 + quad * 4 + i], l);
        #pragma unroll
        for (int nt = 0; nt < 4; ++nt)
            atomicAdd(&Obuf[qh * 16 + quad * 4 + i][nt * 16 + c], O[nt][i]);
    }
    __syncthreads();
    {
        const int r = tid >> 4, d4 = (tid & 15) * 4;
        const float invL = 1.0f / Lbuf[r];
        float4 v = *(float4*)&Obuf[r][d4];
        float4 o = make_float4(v.x * invL, v.y * invL, v.z * invL, v.w * invL);
        *(float4*)&out[((size_t)bb * SEQ + qrow_blk + r) * 64 + d4] = o;
    }
}

extern "C" void kernel_launch(void* const* d_in, const int* in_sizes, int n_in,
                              void* d_out, int out_size, void* d_ws, size_t ws_size,
                              hipStream_t stream)
{
    const float* x    = (const float*)d_in[0];
    const float* Wq   = (const float*)d_in[1];
    const float* bq   = (const float*)d_in[2];
    const float* Wk   = (const float*)d_in[3];
    const float* bk   = (const float*)d_in[4];
    const float* Wv   = (const float*)d_in[5];
    const float* bv   = (const float*)d_in[6];
    const int*   mask = (const int*)d_in[7];
    float* out = (float*)d_out;

    // ws: QF/KF/VF 2MB each + WF 288KB ≈ 6.3 MB
    unsigned short* QF = (unsigned short*)d_ws;
    unsigned short* KF = QF + (size_t)16384 * 64;
    unsigned short* VF = KF + (size_t)16384 * 64;
    unsigned short* WF = VF + (size_t)16384 * 64;

    convert_w_kernel<<<72, 256, 0, stream>>>(Wq, Wk, Wv, WF);
    qkv_proj_kernel<<<512, 256, 0, stream>>>(x, WF, bq, bk, bv, QF, KF, VF);
    attn_kernel<<<512, 512, 0, stream>>>(QF, KF, VF, mask, out);
}

// Round 12
// 174.030 us; speedup vs baseline: 1.0987x; 1.0961x over previous
//
#include <hip/hip_runtime.h>

typedef short  s8v   __attribute__((ext_vector_type(8)));
typedef float  f32x4 __attribute__((ext_vector_type(4)));

#define SEQ 2048
#define WID 768

__device__ __forceinline__ unsigned fbits(float f) {
    union { float f; unsigned u; } v; v.f = f; return v.u;
}
__device__ __forceinline__ float bitsf(unsigned u) {
    union { unsigned u; float f; } v; v.u = u; return v.f;
}
__device__ __forceinline__ unsigned short f2b(float f) {
    unsigned u = fbits(f);
    return (unsigned short)((u + 0x7FFFu + ((u >> 16) & 1u)) >> 16);   // RNE
}
__device__ __forceinline__ unsigned packRNE(float a, float b) {
    unsigned ta = fbits(a) + 0x7FFFu + ((fbits(a) >> 16) & 1u);
    unsigned tb = fbits(b) + 0x7FFFu + ((fbits(b) >> 16) & 1u);
    return __builtin_amdgcn_perm(tb, ta, 0x07060302u);
}
__device__ __forceinline__ unsigned packTRUNC(float a, float b) {
    return __builtin_amdgcn_perm(fbits(b), fbits(a), 0x07060302u);
}
__device__ __forceinline__ f32x4 zero4() { f32x4 z = {0.f, 0.f, 0.f, 0.f}; return z; }

// async global->LDS DMA; per-lane global address, wave-uniform LDS base
__device__ __forceinline__ void async16(const unsigned short* g, void* l) {
    __builtin_amdgcn_global_load_lds(
        (const __attribute__((address_space(1))) unsigned int*)g,
        (__attribute__((address_space(3))) unsigned int*)l, 16, 0, 0);
}
__device__ __forceinline__ void async16f(const float* g, void* l) {
    __builtin_amdgcn_global_load_lds(
        (const __attribute__((address_space(1))) unsigned int*)g,
        (__attribute__((address_space(3))) unsigned int*)l, 16, 0, 0);
}
__device__ __forceinline__ void async4(const unsigned* g, void* l) {
    __builtin_amdgcn_global_load_lds(
        (const __attribute__((address_space(1))) unsigned int*)g,
        (__attribute__((address_space(3))) unsigned int*)l, 4, 0, 0);
}

// ---------------------------------------------------------------------------
// convert_mask: mask -> PM bit-packing (verbatim verified R10 logic).
// ---------------------------------------------------------------------------
__global__ __launch_bounds__(256) void convert_mask_kernel(
    const int* __restrict__ mask, unsigned* __restrict__ PM)
{
    const int tid = threadIdx.x;
    const int gid  = blockIdx.x * 4 + (tid >> 6);
    const int lane = tid & 63, quad = lane >> 4, c = lane & 15;
    const int qb = gid >> 5, kb = gid & 31;
    unsigned w = 0;
    #pragma unroll
    for (int mt = 0; mt < 2; ++mt)
        #pragma unroll
        for (int i = 0; i < 4; ++i) {
            const int q = qb * 32 + mt * 16 + quad * 4 + i;
            const int4 mm = *(const int4*)&mask[(size_t)q * SEQ + kb * 64 + 4 * c];
            if (mm.x) w |= 1u << (mt * 16 + i * 4 + 0);
            if (mm.y) w |= 1u << (mt * 16 + i * 4 + 1);
            if (mm.z) w |= 1u << (mt * 16 + i * 4 + 2);
            if (mm.w) w |= 1u << (mt * 16 + i * 4 + 3);
        }
    PM[(size_t)gid * 64 + lane] = w;
}

// ---------------------------------------------------------------------------
// convert_w: W -> WF bf16 B-frag-tiled (verbatim verified logic).
// ---------------------------------------------------------------------------
__global__ __launch_bounds__(256) void convert_w_kernel(
    const float* __restrict__ Wq, const float* __restrict__ Wk, const float* __restrict__ Wv,
    unsigned short* __restrict__ WF)
{
    const int s2 = blockIdx.x * 256 + threadIdx.x;   // 0 .. 18431
    const int chunk = s2 >> 6, l = s2 & 63;
    const int ntg = chunk / 24, r = chunk - ntg * 24;
    const int kc = r >> 1, h = r & 1;
    const int mat = ntg >> 2;
    const int col = (ntg & 3) * 16 + (l & 15);
    const int k0 = kc * 64 + h * 32 + (l >> 4) * 8;
    const float* Wm = (mat == 0) ? Wq : (mat == 1) ? Wk : Wv;
    float p[8];
    #pragma unroll
    for (int j = 0; j < 8; ++j) p[j] = Wm[(size_t)(k0 + j) * 64 + col];
    uint4 w;
    w.x = packRNE(p[0], p[1]); w.y = packRNE(p[2], p[3]);
    w.z = packRNE(p[4], p[5]); w.w = packRNE(p[6], p[7]);
    *(uint4*)&WF[(size_t)s2 * 8] = w;
}

// ---------------------------------------------------------------------------
// proj: DMA-pipelined bf16 GEMM (verbatim R11, verified).  512 blocks x 256
// thr, 32r x 192c block tile, double-buffered global_load_lds staging,
// one barrier/iter, frag-tiled QF/KF/VF writeback.
// ---------------------------------------------------------------------------
__global__ __launch_bounds__(256, 4) void qkv_proj_kernel(
    const float* __restrict__ x, const unsigned short* __restrict__ WF,
    const float* __restrict__ bq, const float* __restrict__ bk, const float* __restrict__ bv,
    unsigned short* __restrict__ QF, unsigned short* __restrict__ KF,
    unsigned short* __restrict__ VF)
{
    __shared__ __align__(16) unsigned char SM[32768];
    unsigned short (*St)[200] = (unsigned short(*)[200])SM;

    const int tid = threadIdx.x;
    const int wv = tid >> 6, lane = tid & 63, quad = lane >> 4, c = lane & 15;
    const int cg = wv;
    const int rowb = blockIdx.x * 32;

    float bias[3];
    #pragma unroll
    for (int nt = 0; nt < 3; ++nt) {
        int col = cg * 48 + nt * 16 + c;
        const float* B = (col < 64) ? bq : (col < 128) ? bk : bv;
        bias[nt] = B[col & 63];
    }

    auto issue = [&](int kc, int b) {
        unsigned char* base = SM + b * 16384;
        #pragma unroll
        for (int r = 0; r < 4; ++r) {
            const int t = wv * 4 + r;
            if (t < 4) {
                const int mt = t >> 1, jh = t & 1;
                const float* src = x + (size_t)(rowb + mt * 16 + c) * WID
                                     + kc * 32 + quad * 8 + jh * 4;
                async16f(src, base + (mt * 2 + jh) * 1024);
            } else {
                const int i = t - 4;
                const unsigned short* src =
                    WF + (((size_t)i * 12 + (kc >> 1)) * 2 + (kc & 1)) * 512 + lane * 8;
                async16(src, base + 4096 + i * 1024);
            }
        }
    };

    f32x4 acc[2][3];
    #pragma unroll
    for (int mt = 0; mt < 2; ++mt)
        #pragma unroll
        for (int nt = 0; nt < 3; ++nt) acc[mt][nt] = zero4();

    issue(0, 0);
    for (int kc = 0; kc < 24; ++kc) {
        const int b = kc & 1;
        __syncthreads();
        if (kc < 23) issue(kc + 1, b ^ 1);

        const unsigned char* base = SM + b * 16384;
        s8v af[2];
        #pragma unroll
        for (int mt = 0; mt < 2; ++mt) {
            float4 f0 = *(const float4*)(base + (mt * 2 + 0) * 1024 + lane * 16);
            float4 f1 = *(const float4*)(base + (mt * 2 + 1) * 1024 + lane * 16);
            union { uint4 u; s8v v; } a;
            a.u.x = packRNE(f0.x, f0.y);
            a.u.y = packRNE(f0.z, f0.w);
            a.u.z = packRNE(f1.x, f1.y);
            a.u.w = packRNE(f1.z, f1.w);
            af[mt] = a.v;
        }
        s8v bf[3];
        #pragma unroll
        for (int nt = 0; nt < 3; ++nt)
            bf[nt] = *(const s8v*)(base + 4096 + (cg * 3 + nt) * 1024 + lane * 16);
        #pragma unroll
        for (int mt = 0; mt < 2; ++mt)
            #pragma unroll
            for (int nt = 0; nt < 3; ++nt)
                acc[mt][nt] = __builtin_amdgcn_mfma_f32_16x16x32_bf16(
                    af[mt], bf[nt], acc[mt][nt], 0, 0, 0);
    }

    __syncthreads();
    #pragma unroll
    for (int mt = 0; mt < 2; ++mt)
        #pragma unroll
        for (int nt = 0; nt < 3; ++nt)
            #pragma unroll
            for (int i = 0; i < 4; ++i)
                St[mt * 16 + quad * 4 + i][cg * 48 + nt * 16 + c]
                    = f2b(acc[mt][nt][i] + bias[nt]);
    __syncthreads();

    const int kb  = rowb >> 6;
    const int q0k = (rowb & 63) >> 2;
    const int ks0 = (rowb & 63) >> 5;

    {   // QF
        const int g = tid >> 7, ks = (tid >> 6) & 1, l = tid & 63;
        uint4 v = *(uint4*)&St[g * 16 + (l & 15)][ks * 32 + (l >> 4) * 8];
        *(uint4*)&QF[(((size_t)(rowb >> 4) + g) * 2 + ks) * 512 + (size_t)l * 8] = v;
    }
    {   // KF
        const int ksnt = tid >> 5, e = tid & 31;
        const int ks = ksnt >> 2, nt = ksnt & 3;
        const int qd = e >> 3, cc = e & 7;
        uint4 v = *(uint4*)&St[4 * cc + nt][64 + ks * 32 + qd * 8];
        *(uint4*)&KF[(((size_t)kb * 8 + ksnt) * 64 + qd * 16 + q0k + cc) * 8] = v;
    }
    {   // VF
        const int nt = tid >> 6, qd = (tid >> 4) & 3, cc = tid & 15;
        unsigned short p[8];
        #pragma unroll
        for (int s = 0; s < 8; ++s) p[s] = St[qd * 8 + s][128 + nt * 16 + cc];
        uint4 w;
        w.x = (unsigned)p[0] | ((unsigned)p[1] << 16);
        w.y = (unsigned)p[2] | ((unsigned)p[3] << 16);
        w.z = (unsigned)p[4] | ((unsigned)p[5] << 16);
        w.w = (unsigned)p[6] | ((unsigned)p[7] << 16);
        *(uint4*)&VF[(((size_t)kb * 8 + ks0 * 4 + nt) * 64 + qd * 16 + cc) * 8] = w;
    }
}

// ---------------------------------------------------------------------------
// attn: flash attention, MFMA bf16, fixed-shift softmax.  512 thr = 8 waves
// = 4 key-slices x 2 q-halves; block = 32 q x 2048 keys; grid 512 (bb=blk&7
// XCD swizzle) -> 2 blocks/CU.  R12: PM restored (bit-packed mask) and DMA'd
// into LDS per slice-tile with K (async4) - zero VGPR-returning mask loads;
// V consumed in ks-halves of 4 frags (32 transient regs) - no spill.
// 2 barriers/iter; cross-block overlap covers the DMA drain.
// ---------------------------------------------------------------------------
__global__ __launch_bounds__(512, 4) void attn_kernel(
    const unsigned short* __restrict__ QF, const unsigned short* __restrict__ KF,
    const unsigned short* __restrict__ VF, const unsigned* __restrict__ PM,
    float* __restrict__ out)
{
    __shared__ unsigned short Ks[4][4096];              // 8KB per slice
    __shared__ unsigned PMs[4][64];                     // PM words per slice
    __shared__ __align__(16) unsigned char PsOb[17408]; // Ps[8][16][68] ∪ Obuf[32][68]
    __shared__ float Lbuf[32];
    unsigned short (*Ps)[16][68] = (unsigned short(*)[16][68])PsOb;
    float (*Obuf)[68]            = (float(*)[68])PsOb;

    const int tid = threadIdx.x;
    const int wv = tid >> 6, lane = tid & 63, quad = lane >> 4, c = lane & 15;
    const int sl = wv & 3, qh = wv >> 2;
    const int blk = blockIdx.x;
    const int bb = blk & 7, qt = blk >> 3;              // batch, 32-q tile
    const int qrow_blk = qt * 32;

    // Q frags (coalesced 1KB loads)
    s8v qf[2];
    {
        const size_t qgrp = (size_t)bb * 128 + qt * 2 + qh;
        #pragma unroll
        for (int ks = 0; ks < 2; ++ks)
            qf[ks] = *(const s8v*)&QF[(qgrp * 2 + ks) * 512 + (size_t)lane * 8];
    }

    f32x4 O[4];
    float lro[4];
    #pragma unroll
    for (int nt = 0; nt < 4; ++nt) O[nt] = zero4();
    #pragma unroll
    for (int i = 0; i < 4; ++i) lro[i] = 0.f;

    // K + PM DMA for this slice's kt tile: 8 K chunks / 2 waves; PM by qh=0
    auto k_dma = [&](int kt) {
        const size_t kbg = (size_t)bb * 32 + sl * 8 + kt;
        #pragma unroll
        for (int r = 0; r < 4; ++r) {
            const int ch = qh * 4 + r;
            async16(KF + (kbg * 8 + ch) * 512 + lane * 8, &Ks[sl][ch * 512]);
        }
        if (qh == 0)
            async4(PM + ((size_t)qt * 32 + sl * 8 + kt) * 64 + lane, &PMs[sl][0]);
    };

    k_dma(0);
    for (int kt = 0; kt < 8; ++kt) {
        const size_t kbg = (size_t)bb * 32 + sl * 8 + kt;

        __syncthreads();   // publish Ks + PMs (drain DMA)

        // ---- S = Q K^T
        f32x4 S[4];
        #pragma unroll
        for (int nt = 0; nt < 4; ++nt) S[nt] = zero4();
        #pragma unroll
        for (int ks = 0; ks < 2; ++ks) {
            s8v kfr[4];
            #pragma unroll
            for (int nt = 0; nt < 4; ++nt)
                kfr[nt] = *(const s8v*)&Ks[sl][((ks * 4 + nt) * 64 + lane) * 8];
            #pragma unroll
            for (int nt = 0; nt < 4; ++nt)
                S[nt] = __builtin_amdgcn_mfma_f32_16x16x32_bf16(qf[ks], kfr[nt], S[nt], 0, 0, 0);
        }

        // ---- fixed-shift softmax: p = 2^(s*0.125/ln2 - 15/ln2), masked -> 0
        const unsigned pmh = PMs[sl][lane] >> (qh * 16);
        #pragma unroll
        for (int i = 0; i < 4; ++i) {
            float p4[4];
            #pragma unroll
            for (int nt = 0; nt < 4; ++nt) {
                float e = exp2f(fmaf(S[nt][i], 0.18033688011112042f, -21.640425613334451f));
                p4[nt] = ((pmh >> (i * 4 + nt)) & 1u) ? e : 0.f;
            }
            unsigned u0 = packTRUNC(p4[0], p4[1]);
            unsigned u1 = packTRUNC(p4[2], p4[3]);
            lro[i] += bitsf(u0 << 16) + bitsf(u0 & 0xFFFF0000u)
                    + bitsf(u1 << 16) + bitsf(u1 & 0xFFFF0000u);
            *(uint2*)&Ps[wv][quad * 4 + i][4 * c] = make_uint2(u0, u1);
        }

        // ---- O += P V  (V in ks-halves: 4 transient frags, no spill)
        #pragma unroll
        for (int ks = 0; ks < 2; ++ks) {
            s8v vf4[4];
            #pragma unroll
            for (int nt = 0; nt < 4; ++nt)
                vf4[nt] = *(const s8v*)&VF[(kbg * 8 + ks * 4 + nt) * 512 + (size_t)lane * 8];
            s8v a = *(const s8v*)&Ps[wv][c][ks * 32 + quad * 8];
            #pragma unroll
            for (int nt = 0; nt < 4; ++nt)
                O[nt] = __builtin_amdgcn_mfma_f32_16x16x32_bf16(a, vf4[nt], O[nt], 0, 0, 0);
        }

        __syncthreads();   // Ks/PMs reads done
        if (kt < 7) k_dma(kt + 1);
    }

    // ---- merge 4 slices per q-half (Obuf overlays Ps after barrier)
    __syncthreads();
    #pragma unroll
    for (int j = 0; j < 5; ++j) {
        int idx = tid + 512 * j;
        if (idx < 32 * 68) ((float*)Obuf)[idx] = 0.f;
    }
    if (tid < 32) Lbuf[tid] = 0.f;
    __syncthreads();
    #pragma unroll
    for (int i = 0; i < 4; ++i) {
        float l = lro[i];
        l += __shfl_xor(l, 1);
        l += __shfl_xor(l, 2);
        l += __shfl_xor(l, 4);
        l += __shfl_xor(l, 8);
        if (c == 0) atomicAdd(&Lbuf[qh * 16 + quad * 4 + i], l);
        #pragma unroll
        for (int nt = 0; nt < 4; ++nt)
            atomicAdd(&Obuf[qh * 16 + quad * 4 + i][nt * 16 + c], O[nt][i]);
    }
    __syncthreads();
    {
        const int r = tid >> 4, d4 = (tid & 15) * 4;
        const float invL = 1.0f / Lbuf[r];
        float4 v = *(float4*)&Obuf[r][d4];
        float4 o = make_float4(v.x * invL, v.y * invL, v.z * invL, v.w * invL);
        *(float4*)&out[((size_t)bb * SEQ + qrow_blk + r) * 64 + d4] = o;
    }
}

extern "C" void kernel_launch(void* const* d_in, const int* in_sizes, int n_in,
                              void* d_out, int out_size, void* d_ws, size_t ws_size,
                              hipStream_t stream)
{
    const float* x    = (const float*)d_in[0];
    const float* Wq   = (const float*)d_in[1];
    const float* bq   = (const float*)d_in[2];
    const float* Wk   = (const float*)d_in[3];
    const float* bk   = (const float*)d_in[4];
    const float* Wv   = (const float*)d_in[5];
    const float* bv   = (const float*)d_in[6];
    const int*   mask = (const int*)d_in[7];
    float* out = (float*)d_out;

    // ws: QF/KF/VF 2MB each + WF 288KB + PM 512KB ≈ 6.8 MB
    unsigned short* QF = (unsigned short*)d_ws;
    unsigned short* KF = QF + (size_t)16384 * 64;
    unsigned short* VF = KF + (size_t)16384 * 64;
    unsigned short* WF = VF + (size_t)16384 * 64;
    unsigned*       PM = (unsigned*)(WF + (size_t)192 * WID);

    convert_mask_kernel<<<512, 256, 0, stream>>>(mask, PM);
    convert_w_kernel<<<72, 256, 0, stream>>>(Wq, Wk, Wv, WF);
    qkv_proj_kernel<<<512, 256, 0, stream>>>(x, WF, bq, bk, bv, QF, KF, VF);
    attn_kernel<<<512, 512, 0, stream>>>(QF, KF, VF, PM, out);
}

// Round 13
// 164.341 us; speedup vs baseline: 1.1634x; 1.0590x over previous
//
#include <hip/hip_runtime.h>

typedef short  s8v   __attribute__((ext_vector_type(8)));
typedef float  f32x4 __attribute__((ext_vector_type(4)));

#define SEQ 2048
#define WID 768

__device__ __forceinline__ unsigned fbits(float f) {
    union { float f; unsigned u; } v; v.f = f; return v.u;
}
__device__ __forceinline__ float bitsf(unsigned u) {
    union { unsigned u; float f; } v; v.u = u; return v.f;
}
__device__ __forceinline__ unsigned short f2b(float f) {
    unsigned u = fbits(f);
    return (unsigned short)((u + 0x7FFFu + ((u >> 16) & 1u)) >> 16);   // RNE
}
__device__ __forceinline__ unsigned packRNE(float a, float b) {
    unsigned ta = fbits(a) + 0x7FFFu + ((fbits(a) >> 16) & 1u);
    unsigned tb = fbits(b) + 0x7FFFu + ((fbits(b) >> 16) & 1u);
    return __builtin_amdgcn_perm(tb, ta, 0x07060302u);
}
__device__ __forceinline__ unsigned packTRUNC(float a, float b) {
    return __builtin_amdgcn_perm(fbits(b), fbits(a), 0x07060302u);
}
__device__ __forceinline__ f32x4 zero4() { f32x4 z = {0.f, 0.f, 0.f, 0.f}; return z; }

// async global->LDS DMA; per-lane global address, wave-uniform LDS base
__device__ __forceinline__ void async16(const unsigned short* g, void* l) {
    __builtin_amdgcn_global_load_lds(
        (const __attribute__((address_space(1))) unsigned int*)g,
        (__attribute__((address_space(3))) unsigned int*)l, 16, 0, 0);
}
__device__ __forceinline__ void async16f(const float* g, void* l) {
    __builtin_amdgcn_global_load_lds(
        (const __attribute__((address_space(1))) unsigned int*)g,
        (__attribute__((address_space(3))) unsigned int*)l, 16, 0, 0);
}
__device__ __forceinline__ void async4(const unsigned* g, void* l) {
    __builtin_amdgcn_global_load_lds(
        (const __attribute__((address_space(1))) unsigned int*)g,
        (__attribute__((address_space(3))) unsigned int*)l, 4, 0, 0);
}

// ---------------------------------------------------------------------------
// convert: [0,512) mask -> PM (verbatim verified); [512,584) W -> WF
// bf16 B-frag-tiled (verbatim verified).  Merged: one launch, co-scheduled.
// ---------------------------------------------------------------------------
__global__ __launch_bounds__(256) void convert_kernel(
    const int* __restrict__ mask,
    const float* __restrict__ Wq, const float* __restrict__ Wk, const float* __restrict__ Wv,
    unsigned* __restrict__ PM, unsigned short* __restrict__ WF)
{
    const int tid = threadIdx.x;
    const int blk = blockIdx.x;
    if (blk < 512) {
        const int gid  = blk * 4 + (tid >> 6);
        const int lane = tid & 63, quad = lane >> 4, c = lane & 15;
        const int qb = gid >> 5, kb = gid & 31;
        unsigned w = 0;
        #pragma unroll
        for (int mt = 0; mt < 2; ++mt)
            #pragma unroll
            for (int i = 0; i < 4; ++i) {
                const int q = qb * 32 + mt * 16 + quad * 4 + i;
                const int4 mm = *(const int4*)&mask[(size_t)q * SEQ + kb * 64 + 4 * c];
                if (mm.x) w |= 1u << (mt * 16 + i * 4 + 0);
                if (mm.y) w |= 1u << (mt * 16 + i * 4 + 1);
                if (mm.z) w |= 1u << (mt * 16 + i * 4 + 2);
                if (mm.w) w |= 1u << (mt * 16 + i * 4 + 3);
            }
        PM[(size_t)gid * 64 + lane] = w;
    } else {
        const int s2 = (blk - 512) * 256 + tid;       // 0 .. 18431
        const int chunk = s2 >> 6, l = s2 & 63;
        const int ntg = chunk / 24, r = chunk - ntg * 24;
        const int kc = r >> 1, h = r & 1;
        const int mat = ntg >> 2;
        const int col = (ntg & 3) * 16 + (l & 15);
        const int k0 = kc * 64 + h * 32 + (l >> 4) * 8;
        const float* Wm = (mat == 0) ? Wq : (mat == 1) ? Wk : Wv;
        float p[8];
        #pragma unroll
        for (int j = 0; j < 8; ++j) p[j] = Wm[(size_t)(k0 + j) * 64 + col];
        uint4 w;
        w.x = packRNE(p[0], p[1]); w.y = packRNE(p[2], p[3]);
        w.z = packRNE(p[4], p[5]); w.w = packRNE(p[6], p[7]);
        *(uint4*)&WF[(size_t)s2 * 8] = w;
    }
}

// ---------------------------------------------------------------------------
// proj: DMA-pipelined bf16 GEMM, BK=64 (12 iters).  512 blocks x 256 thr
// (2 blocks/CU @64KB LDS).  Block 32r x 192c; wave 32r x 48c (cg = wv).
// Both operands via global_load_lds; double-buffered (32KB/buf); DMA for
// kc+1 issued right AFTER the publish barrier of kc -> full compute phase
// of slack; ONE barrier/iter.  Epilogue: verified frag-tiled writeback.
// ---------------------------------------------------------------------------
__global__ __launch_bounds__(256, 2) void qkv_proj_kernel(
    const float* __restrict__ x, const unsigned short* __restrict__ WF,
    const float* __restrict__ bq, const float* __restrict__ bk, const float* __restrict__ bv,
    unsigned short* __restrict__ QF, unsigned short* __restrict__ KF,
    unsigned short* __restrict__ VF)
{
    __shared__ __align__(16) unsigned char SM[65536];   // 2 x (8KB A + 24KB B)
    unsigned short (*St)[200] = (unsigned short(*)[200])SM;

    const int tid = threadIdx.x;
    const int wv = tid >> 6, lane = tid & 63, quad = lane >> 4, c = lane & 15;
    const int cg = wv;
    const int rowb = blockIdx.x * 32;

    float bias[3];
    #pragma unroll
    for (int nt = 0; nt < 3; ++nt) {
        int col = cg * 48 + nt * 16 + c;
        const float* B = (col < 64) ? bq : (col < 128) ? bk : bv;
        bias[nt] = B[col & 63];
    }

    // 32 chunks/iter (8 A fp32-gather + 24 B contiguous), 8 per wave
    auto issue = [&](int kc, int b) {
        unsigned char* base = SM + b * 32768;
        #pragma unroll
        for (int r = 0; r < 8; ++r) {
            const int t = wv * 8 + r;
            if (t < 8) {          // A chunk t: g = t>>2, kh = (t>>1)&1, jh = t&1
                const int g = t >> 2, kh = (t >> 1) & 1, jh = t & 1;
                const float* src = x + (size_t)(rowb + g * 16 + c) * WID
                                     + kc * 64 + kh * 32 + quad * 8 + jh * 4;
                async16f(src, base + t * 1024);
            } else {              // B chunk i = t-8: ntg = i>>1, kh = i&1
                const int i = t - 8, ntg = i >> 1, kh = i & 1;
                const unsigned short* src =
                    WF + (((size_t)ntg * 12 + kc) * 2 + kh) * 512 + lane * 8;
                async16(src, base + 8192 + i * 1024);
            }
        }
    };

    f32x4 acc[2][3];
    #pragma unroll
    for (int mt = 0; mt < 2; ++mt)
        #pragma unroll
        for (int nt = 0; nt < 3; ++nt) acc[mt][nt] = zero4();

    issue(0, 0);
    for (int kc = 0; kc < 12; ++kc) {
        const int b = kc & 1;
        __syncthreads();                      // publish buf b (slack = full phase)
        if (kc < 11) issue(kc + 1, b ^ 1);    // drains at NEXT barrier

        const unsigned char* base = SM + b * 32768;
        #pragma unroll
        for (int kh = 0; kh < 2; ++kh) {
            s8v af[2];
            #pragma unroll
            for (int mt = 0; mt < 2; ++mt) {
                float4 f0 = *(const float4*)(base + (mt * 4 + kh * 2 + 0) * 1024 + lane * 16);
                float4 f1 = *(const float4*)(base + (mt * 4 + kh * 2 + 1) * 1024 + lane * 16);
                union { uint4 u; s8v v; } a;
                a.u.x = packRNE(f0.x, f0.y);
                a.u.y = packRNE(f0.z, f0.w);
                a.u.z = packRNE(f1.x, f1.y);
                a.u.w = packRNE(f1.z, f1.w);
                af[mt] = a.v;
            }
            s8v bf[3];
            #pragma unroll
            for (int nt = 0; nt < 3; ++nt)
                bf[nt] = *(const s8v*)(base + 8192 + ((cg * 3 + nt) * 2 + kh) * 1024 + lane * 16);
            #pragma unroll
            for (int mt = 0; mt < 2; ++mt)
                #pragma unroll
                for (int nt = 0; nt < 3; ++nt)
                    acc[mt][nt] = __builtin_amdgcn_mfma_f32_16x16x32_bf16(
                        af[mt], bf[nt], acc[mt][nt], 0, 0, 0);
        }
    }

    // ---- epilogue (verbatim verified R12): stage 32x192 bf16 tile, writeback
    __syncthreads();
    #pragma unroll
    for (int mt = 0; mt < 2; ++mt)
        #pragma unroll
        for (int nt = 0; nt < 3; ++nt)
            #pragma unroll
            for (int i = 0; i < 4; ++i)
                St[mt * 16 + quad * 4 + i][cg * 48 + nt * 16 + c]
                    = f2b(acc[mt][nt][i] + bias[nt]);
    __syncthreads();

    const int kb  = rowb >> 6;
    const int q0k = (rowb & 63) >> 2;
    const int ks0 = (rowb & 63) >> 5;

    {   // QF
        const int g = tid >> 7, ks = (tid >> 6) & 1, l = tid & 63;
        uint4 v = *(uint4*)&St[g * 16 + (l & 15)][ks * 32 + (l >> 4) * 8];
        *(uint4*)&QF[(((size_t)(rowb >> 4) + g) * 2 + ks) * 512 + (size_t)l * 8] = v;
    }
    {   // KF
        const int ksnt = tid >> 5, e = tid & 31;
        const int ks = ksnt >> 2, nt = ksnt & 3;
        const int qd = e >> 3, cc = e & 7;
        uint4 v = *(uint4*)&St[4 * cc + nt][64 + ks * 32 + qd * 8];
        *(uint4*)&KF[(((size_t)kb * 8 + ksnt) * 64 + qd * 16 + q0k + cc) * 8] = v;
    }
    {   // VF
        const int nt = tid >> 6, qd = (tid >> 4) & 3, cc = tid & 15;
        unsigned short p[8];
        #pragma unroll
        for (int s = 0; s < 8; ++s) p[s] = St[qd * 8 + s][128 + nt * 16 + cc];
        uint4 w;
        w.x = (unsigned)p[0] | ((unsigned)p[1] << 16);
        w.y = (unsigned)p[2] | ((unsigned)p[3] << 16);
        w.z = (unsigned)p[4] | ((unsigned)p[5] << 16);
        w.w = (unsigned)p[6] | ((unsigned)p[7] << 16);
        *(uint4*)&VF[(((size_t)kb * 8 + ks0 * 4 + nt) * 64 + qd * 16 + cc) * 8] = w;
    }
}

// ---------------------------------------------------------------------------
// attn: flash attention, MFMA bf16, fixed-shift softmax (verbatim verified
// math).  1024 thr = 16 waves = 4 key-slices x 4 q-groups (64q x 2048k per
// block); grid 256 (bb = blk&7), 1 block/CU.  TRUE pipeline: double-buffered
// K+PM DMA issued right AFTER the publish barrier -> a full compute phase of
// slack; ONE barrier per iteration, so waves run free between barriers and
// cross-hide the transient V-load latency.  V in ks-halves (no spill,
// proven R12).  LDS ~102 KB.
// ---------------------------------------------------------------------------
__global__ __launch_bounds__(1024, 4) void attn_kernel(
    const unsigned short* __restrict__ QF, const unsigned short* __restrict__ KF,
    const unsigned short* __restrict__ VF, const unsigned* __restrict__ PM,
    float* __restrict__ out)
{
    __shared__ unsigned short Ks[2][4][4096];            // 64 KB K double-buffer
    __shared__ unsigned PMs[2][2][4][64];                // 4 KB PM double-buffer
    __shared__ __align__(16) unsigned char PsOb[34816];  // Ps[16][16][68] ∪ Obuf[64][68]
    __shared__ float Lbuf[64];
    unsigned short (*Ps)[16][68] = (unsigned short(*)[16][68])PsOb;
    float (*Obuf)[68]            = (float(*)[68])PsOb;

    const int tid = threadIdx.x;
    const int wv = tid >> 6, lane = tid & 63, quad = lane >> 4, c = lane & 15;
    const int sl = wv & 3, qg = wv >> 2, mt = qg & 1;
    const int blk = blockIdx.x;
    const int bb = blk & 7, qt = blk >> 3;               // batch, 64-q tile [0,32)

    // Q frags (coalesced 1KB loads)
    s8v qf[2];
    {
        const size_t qgrp = (size_t)bb * 128 + qt * 4 + qg;
        #pragma unroll
        for (int ks = 0; ks < 2; ++ks)
            qf[ks] = *(const s8v*)&QF[(qgrp * 2 + ks) * 512 + (size_t)lane * 8];
    }

    f32x4 O[4];
    float lro[4];
    #pragma unroll
    for (int nt = 0; nt < 4; ++nt) O[nt] = zero4();
    #pragma unroll
    for (int i = 0; i < 4; ++i) lro[i] = 0.f;

    // K + PM DMA for tile kt into buffer b (8 K chunks / 4 qg waves = 2 each)
    auto dma = [&](int kt, int b) {
        const size_t kbg = (size_t)bb * 32 + sl * 8 + kt;
        #pragma unroll
        for (int r = 0; r < 2; ++r) {
            const int ch = qg * 2 + r;
            async16(KF + (kbg * 8 + ch) * 512 + lane * 8, &Ks[b][sl][ch * 512]);
        }
        if (qg == 0)
            async4(PM + ((size_t)(qt * 2 + 0) * 32 + sl * 8 + kt) * 64 + lane,
                   &PMs[b][0][sl][0]);
        if (qg == 2)
            async4(PM + ((size_t)(qt * 2 + 1) * 32 + sl * 8 + kt) * 64 + lane,
                   &PMs[b][1][sl][0]);
    };

    dma(0, 0);
    for (int kt = 0; kt < 8; ++kt) {
        const int b = kt & 1;
        __syncthreads();                      // publish Ks/PMs buf b
        if (kt < 7) dma(kt + 1, b ^ 1);       // drains at NEXT barrier (full phase)

        const size_t kbg = (size_t)bb * 32 + sl * 8 + kt;

        // ---- S = Q K^T
        f32x4 S[4];
        #pragma unroll
        for (int nt = 0; nt < 4; ++nt) S[nt] = zero4();
        #pragma unroll
        for (int ks = 0; ks < 2; ++ks) {
            s8v kfr[4];
            #pragma unroll
            for (int nt = 0; nt < 4; ++nt)
                kfr[nt] = *(const s8v*)&Ks[b][sl][((ks * 4 + nt) * 64 + lane) * 8];
            #pragma unroll
            for (int nt = 0; nt < 4; ++nt)
                S[nt] = __builtin_amdgcn_mfma_f32_16x16x32_bf16(qf[ks], kfr[nt], S[nt], 0, 0, 0);
        }

        // ---- fixed-shift softmax: p = 2^(s*0.125/ln2 - 15/ln2), masked -> 0
        const unsigned pmh = PMs[b][qg >> 1][sl][lane] >> (mt * 16);
        #pragma unroll
        for (int i = 0; i < 4; ++i) {
            float p4[4];
            #pragma unroll
            for (int nt = 0; nt < 4; ++nt) {
                float e = exp2f(fmaf(S[nt][i], 0.18033688011112042f, -21.640425613334451f));
                p4[nt] = ((pmh >> (i * 4 + nt)) & 1u) ? e : 0.f;
            }
            unsigned u0 = packTRUNC(p4[0], p4[1]);
            unsigned u1 = packTRUNC(p4[2], p4[3]);
            lro[i] += bitsf(u0 << 16) + bitsf(u0 & 0xFFFF0000u)
                    + bitsf(u1 << 16) + bitsf(u1 & 0xFFFF0000u);
            *(uint2*)&Ps[wv][quad * 4 + i][4 * c] = make_uint2(u0, u1);
        }

        // ---- O += P V  (V in ks-halves: transient frags, no spill)
        #pragma unroll
        for (int ks = 0; ks < 2; ++ks) {
            s8v vf4[4];
            #pragma unroll
            for (int nt = 0; nt < 4; ++nt)
                vf4[nt] = *(const s8v*)&VF[(kbg * 8 + ks * 4 + nt) * 512 + (size_t)lane * 8];
            s8v a = *(const s8v*)&Ps[wv][c][ks * 32 + quad * 8];
            #pragma unroll
            for (int nt = 0; nt < 4; ++nt)
                O[nt] = __builtin_amdgcn_mfma_f32_16x16x32_bf16(a, vf4[nt], O[nt], 0, 0, 0);
        }
    }

    // ---- merge 4 slices per q-group (Obuf overlays Ps after barrier)
    __syncthreads();
    #pragma unroll
    for (int j = 0; j < 5; ++j) {
        int idx = tid + 1024 * j;
        if (idx < 64 * 68) ((float*)Obuf)[idx] = 0.f;
    }
    if (tid < 64) Lbuf[tid] = 0.f;
    __syncthreads();
    #pragma unroll
    for (int i = 0; i < 4; ++i) {
        float l = lro[i];
        l += __shfl_xor(l, 1);
        l += __shfl_xor(l, 2);
        l += __shfl_xor(l, 4);
        l += __shfl_xor(l, 8);
        if (c == 0) atomicAdd(&Lbuf[qg * 16 + quad * 4 + i], l);
        #pragma unroll
        for (int nt = 0; nt < 4; ++nt)
            atomicAdd(&Obuf[qg * 16 + quad * 4 + i][nt * 16 + c], O[nt][i]);
    }
    __syncthreads();
    {
        const int r = tid >> 4, d4 = (tid & 15) * 4;
        const float invL = 1.0f / Lbuf[r];
        float4 v = *(float4*)&Obuf[r][d4];
        float4 o = make_float4(v.x * invL, v.y * invL, v.z * invL, v.w * invL);
        *(float4*)&out[((size_t)bb * SEQ + qt * 64 + r) * 64 + d4] = o;
    }
}

extern "C" void kernel_launch(void* const* d_in, const int* in_sizes, int n_in,
                              void* d_out, int out_size, void* d_ws, size_t ws_size,
                              hipStream_t stream)
{
    const float* x    = (const float*)d_in[0];
    const float* Wq   = (const float*)d_in[1];
    const float* bq   = (const float*)d_in[2];
    const float* Wk   = (const float*)d_in[3];
    const float* bk   = (const float*)d_in[4];
    const float* Wv   = (const float*)d_in[5];
    const float* bv   = (const float*)d_in[6];
    const int*   mask = (const int*)d_in[7];
    float* out = (float*)d_out;

    // ws: QF/KF/VF 2MB each + WF 288KB + PM 512KB ≈ 6.8 MB
    unsigned short* QF = (unsigned short*)d_ws;
    unsigned short* KF = QF + (size_t)16384 * 64;
    unsigned short* VF = KF + (size_t)16384 * 64;
    unsigned short* WF = VF + (size_t)16384 * 64;
    unsigned*       PM = (unsigned*)(WF + (size_t)192 * WID);

    convert_kernel<<<584, 256, 0, stream>>>(mask, Wq, Wk, Wv, PM, WF);
    qkv_proj_kernel<<<512, 256, 0, stream>>>(x, WF, bq, bk, bv, QF, KF, VF);
    attn_kernel<<<256, 1024, 0, stream>>>(QF, KF, VF, PM, out);
}